// Round 1
// baseline (409.057 us; speedup 1.0000x reference)
//
#include <hip/hip_runtime.h>

// ---------------------------------------------------------------------------
// GCN 2-layer: h1 = relu(LN(Ahat @ (x W1) + b1)); out = Ahat @ (h1 W2) + b2
// Ahat = D^-1/2 (A+I) D^-1/2, CSR built on-device each call (no feature atomics)
// ---------------------------------------------------------------------------

__global__ void count_k(const int* __restrict__ dst, int* __restrict__ cnt, int e) {
    int i = blockIdx.x * blockDim.x + threadIdx.x;
    if (i < e) atomicAdd(&cnt[dst[i]], 1);
}

__global__ __launch_bounds__(1024) void scan_k(const int* __restrict__ cnt,
                                               int* __restrict__ offs,
                                               int* __restrict__ cursor,
                                               float* __restrict__ dinv, int n) {
    __shared__ int part[1024];
    int t = threadIdx.x;
    int chunk = (n + 1023) >> 10;
    int lo = t * chunk;
    int hi = min(lo + chunk, n);
    int s = 0;
    for (int i = lo; i < hi; ++i) s += cnt[i];
    part[t] = s;
    __syncthreads();
    for (int d = 1; d < 1024; d <<= 1) {
        int v = (t >= d) ? part[t - d] : 0;
        __syncthreads();
        part[t] += v;
        __syncthreads();
    }
    int pre = (t == 0) ? 0 : part[t - 1];
    for (int i = lo; i < hi; ++i) {
        int c = cnt[i];
        offs[i] = pre;
        cursor[i] = pre;
        dinv[i] = rsqrtf((float)(c + 1));   // deg includes self loop
        pre += c;
    }
    if (t == 1023) offs[n] = part[1023];
}

__global__ void fill_k(const int* __restrict__ src, const int* __restrict__ dst,
                       int* __restrict__ cursor, const float* __restrict__ dinv,
                       int2* __restrict__ edge, int e) {
    int i = blockIdx.x * blockDim.x + threadIdx.x;
    if (i >= e) return;
    int s = src[i], d = dst[i];
    int pos = atomicAdd(&cursor[d], 1);
    edge[pos] = make_int2(s, __float_as_int(dinv[s] * dinv[d]));
}

// Row-per-thread GEMM: X[n,128] @ W[128,M] -> H[n,M]. W indices are
// lane-uniform -> compiler emits scalar (s_load) broadcasts; no LDS needed.
template<int M>
__global__ __launch_bounds__(256) void gemm_rt(const float* __restrict__ X,
                                               const float* __restrict__ W,
                                               float* __restrict__ H, int n) {
    int r = blockIdx.x * 256 + threadIdx.x;
    if (r >= n) return;
    int c0 = blockIdx.y * 32;
    const float4* X4 = (const float4*)X;
    float acc[32];
#pragma unroll
    for (int j = 0; j < 32; ++j) acc[j] = 0.f;
    for (int k4 = 0; k4 < 32; ++k4) {
        float4 xv = X4[r * 32 + k4];
        const float* Wp = &W[(k4 * 4) * M + c0];
#pragma unroll
        for (int kk = 0; kk < 4; ++kk) {
            float xk = (kk == 0) ? xv.x : (kk == 1) ? xv.y : (kk == 2) ? xv.z : xv.w;
#pragma unroll
            for (int j = 0; j < 32; ++j)
                acc[j] = fmaf(xk, Wp[kk * M + j], acc[j]);
        }
    }
#pragma unroll
    for (int j = 0; j < 32; j += 4)
        *(float4*)&H[(size_t)r * M + c0 + j] =
            make_float4(acc[j], acc[j + 1], acc[j + 2], acc[j + 3]);
}

// Layer 1 propagation + bias + LayerNorm + ReLU. One wave per node,
// lane holds features {2*lane, 2*lane+1}.
__global__ __launch_bounds__(256) void prop_ln(const float* __restrict__ h0,
                                               const int* __restrict__ offs,
                                               const int2* __restrict__ edge,
                                               const float* __restrict__ dinv,
                                               const float* __restrict__ b1,
                                               const float* __restrict__ gamma,
                                               const float* __restrict__ beta,
                                               float* __restrict__ h1, int n) {
    int wid = __builtin_amdgcn_readfirstlane((blockIdx.x * blockDim.x + threadIdx.x) >> 6);
    int lane = threadIdx.x & 63;
    if (wid >= n) return;
    const float2* __restrict__ h02 = (const float2*)h0;
    float di = dinv[wid];
    float2 v = h02[wid * 64 + lane];
    float a0 = v.x * di * di;      // self loop, norm = dinv^2
    float a1 = v.y * di * di;
    int s0 = offs[wid], s1 = offs[wid + 1];
    for (int k = s0; k < s1; ++k) {
        int2 ed = edge[k];         // wave-uniform -> scalar load
        float w = __int_as_float(ed.y);
        float2 u = h02[ed.x * 64 + lane];
        a0 = fmaf(u.x, w, a0);
        a1 = fmaf(u.y, w, a1);
    }
    a0 += b1[2 * lane];
    a1 += b1[2 * lane + 1];
    // LayerNorm over 128 features spread across the 64-lane wave
    float sum = a0 + a1, sq = a0 * a0 + a1 * a1;
#pragma unroll
    for (int off = 32; off > 0; off >>= 1) {
        sum += __shfl_xor(sum, off);
        sq  += __shfl_xor(sq, off);
    }
    float mu  = sum * (1.f / 128.f);
    float var = fmaxf(sq * (1.f / 128.f) - mu * mu, 0.f);
    float rstd = rsqrtf(var + 1e-6f);
    float y0 = fmaxf((a0 - mu) * rstd * gamma[2 * lane] + beta[2 * lane], 0.f);
    float y1 = fmaxf((a1 - mu) * rstd * gamma[2 * lane + 1] + beta[2 * lane + 1], 0.f);
    ((float2*)h1)[wid * 64 + lane] = make_float2(y0, y1);
}

// Layer 2 propagation + bias. One wave per node, lane = feature (64).
__global__ __launch_bounds__(256) void prop_out(const float* __restrict__ h2,
                                                const int* __restrict__ offs,
                                                const int2* __restrict__ edge,
                                                const float* __restrict__ dinv,
                                                const float* __restrict__ b2,
                                                float* __restrict__ out, int n) {
    int wid = __builtin_amdgcn_readfirstlane((blockIdx.x * blockDim.x + threadIdx.x) >> 6);
    int lane = threadIdx.x & 63;
    if (wid >= n) return;
    float di = dinv[wid];
    float a = h2[wid * 64 + lane] * di * di;
    int s0 = offs[wid], s1 = offs[wid + 1];
    for (int k = s0; k < s1; ++k) {
        int2 ed = edge[k];
        a = fmaf(h2[ed.x * 64 + lane], __int_as_float(ed.y), a);
    }
    out[wid * 64 + lane] = a + b2[lane];
}

extern "C" void kernel_launch(void* const* d_in, const int* in_sizes, int n_in,
                              void* d_out, int out_size, void* d_ws, size_t ws_size,
                              hipStream_t stream) {
    const float* x     = (const float*)d_in[0];
    const int*   ei    = (const int*)d_in[1];
    const float* W1    = (const float*)d_in[2];
    const float* b1    = (const float*)d_in[3];
    const float* gam   = (const float*)d_in[4];
    const float* bet   = (const float*)d_in[5];
    const float* W2    = (const float*)d_in[6];
    const float* b2    = (const float*)d_in[7];
    float* out = (float*)d_out;

    int n = in_sizes[0] / 128;   // 50000
    int e = in_sizes[1] / 2;     // 800000
    const int* src = ei;
    const int* dst = ei + e;

    char* p = (char*)d_ws;
    auto alloc = [&](size_t bytes) {
        void* q = (void*)p;
        p += (bytes + 255) & ~(size_t)255;
        return q;
    };
    int*   cnt    = (int*)alloc((size_t)n * 4);
    int*   offs   = (int*)alloc((size_t)(n + 1) * 4);
    int*   cursor = (int*)alloc((size_t)n * 4);
    float* dinv   = (float*)alloc((size_t)n * 4);
    int2*  edge   = (int2*)alloc((size_t)e * 8);
    float* h0     = (float*)alloc((size_t)n * 128 * 4);
    float* h1     = (float*)alloc((size_t)n * 128 * 4);
    float* h2     = h0;  // reuse: h0 dead after prop_ln

    hipMemsetAsync(cnt, 0, (size_t)n * 4, stream);
    count_k<<<(e + 255) / 256, 256, 0, stream>>>(dst, cnt, e);
    scan_k<<<1, 1024, 0, stream>>>(cnt, offs, cursor, dinv, n);
    fill_k<<<(e + 255) / 256, 256, 0, stream>>>(src, dst, cursor, dinv, edge, e);

    gemm_rt<128><<<dim3((n + 255) / 256, 4), 256, 0, stream>>>(x, W1, h0, n);
    prop_ln<<<(n + 3) / 4, 256, 0, stream>>>(h0, offs, edge, dinv, b1, gam, bet, h1, n);
    gemm_rt<64><<<dim3((n + 255) / 256, 2), 256, 0, stream>>>(h1, W2, h2, n);
    prop_out<<<(n + 3) / 4, 256, 0, stream>>>(h2, offs, edge, dinv, b2, out, n);
}

// Round 2
// 313.965 us; speedup vs baseline: 1.3029x; 1.3029x over previous
//
#include <hip/hip_runtime.h>

// ---------------------------------------------------------------------------
// GCN 2-layer: h1 = relu(LN(Ahat @ (x W1) + b1)); out = Ahat @ (h1 W2) + b2
// Ahat = D^-1/2 (A+I) D^-1/2, CSR built on-device each call (no feature atomics)
// Round 1: single-block scan_k (133us, 1 CU) -> 3-kernel hierarchical scan.
// ---------------------------------------------------------------------------

__global__ void count_k(const int* __restrict__ dst, int* __restrict__ cnt, int e) {
    int i = blockIdx.x * blockDim.x + threadIdx.x;
    if (i < e) atomicAdd(&cnt[dst[i]], 1);
}

// Pass 1: per-block inclusive scan of cnt -> incl, block totals -> bsum.
__global__ __launch_bounds__(1024) void scan1_k(const int* __restrict__ cnt,
                                                int* __restrict__ incl,
                                                int* __restrict__ bsum, int n) {
    __shared__ int lds[1024];
    int t = threadIdx.x;
    int i = blockIdx.x * 1024 + t;
    int v = (i < n) ? cnt[i] : 0;
    lds[t] = v;
    __syncthreads();
#pragma unroll
    for (int d = 1; d < 1024; d <<= 1) {
        int u = (t >= d) ? lds[t - d] : 0;
        __syncthreads();
        lds[t] += u;
        __syncthreads();
    }
    if (i < n) incl[i] = lds[t];
    if (t == 1023) bsum[blockIdx.x] = lds[1023];
}

// Pass 2: exclusive scan of the 64 block sums (single wave).
__global__ __launch_bounds__(64) void scan2_k(const int* __restrict__ bsum,
                                              int* __restrict__ bpre, int nb) {
    int t = threadIdx.x;
    int v = (t < nb) ? bsum[t] : 0;
#pragma unroll
    for (int d = 1; d < 64; d <<= 1) {
        int u = __shfl_up(v, d);
        if (t >= d) v += u;
    }
    if (t < nb) bpre[t] = v - bsum[t];   // exclusive
}

// Pass 3: offs/cursor (exclusive prefix), dinv, sentinel offs[n].
__global__ __launch_bounds__(1024) void scan3_k(const int* __restrict__ cnt,
                                                const int* __restrict__ incl,
                                                const int* __restrict__ bpre,
                                                int* __restrict__ offs,
                                                int* __restrict__ cursor,
                                                float* __restrict__ dinv, int n) {
    int i = blockIdx.x * 1024 + threadIdx.x;
    if (i >= n) return;
    int c = cnt[i];
    int inc = incl[i] + bpre[blockIdx.x];
    int ex = inc - c;
    offs[i] = ex;
    cursor[i] = ex;
    dinv[i] = rsqrtf((float)(c + 1));    // deg includes self loop
    if (i == n - 1) offs[n] = inc;
}

__global__ void fill_k(const int* __restrict__ src, const int* __restrict__ dst,
                       int* __restrict__ cursor, const float* __restrict__ dinv,
                       int2* __restrict__ edge, int e) {
    int i = blockIdx.x * blockDim.x + threadIdx.x;
    if (i >= e) return;
    int s = src[i], d = dst[i];
    int pos = atomicAdd(&cursor[d], 1);
    edge[pos] = make_int2(s, __float_as_int(dinv[s] * dinv[d]));
}

// Row-per-thread GEMM: X[n,128] @ W[128,M] -> H[n,M]. W indices are
// lane-uniform -> compiler emits scalar (s_load) broadcasts; no LDS needed.
template<int M>
__global__ __launch_bounds__(256) void gemm_rt(const float* __restrict__ X,
                                               const float* __restrict__ W,
                                               float* __restrict__ H, int n) {
    int r = blockIdx.x * 256 + threadIdx.x;
    if (r >= n) return;
    int c0 = blockIdx.y * 32;
    const float4* X4 = (const float4*)X;
    float acc[32];
#pragma unroll
    for (int j = 0; j < 32; ++j) acc[j] = 0.f;
    for (int k4 = 0; k4 < 32; ++k4) {
        float4 xv = X4[r * 32 + k4];
        const float* Wp = &W[(k4 * 4) * M + c0];
#pragma unroll
        for (int kk = 0; kk < 4; ++kk) {
            float xk = (kk == 0) ? xv.x : (kk == 1) ? xv.y : (kk == 2) ? xv.z : xv.w;
#pragma unroll
            for (int j = 0; j < 32; ++j)
                acc[j] = fmaf(xk, Wp[kk * M + j], acc[j]);
        }
    }
#pragma unroll
    for (int j = 0; j < 32; j += 4)
        *(float4*)&H[(size_t)r * M + c0 + j] =
            make_float4(acc[j], acc[j + 1], acc[j + 2], acc[j + 3]);
}

// Layer 1 propagation + bias + LayerNorm + ReLU. One wave per node,
// lane holds features {2*lane, 2*lane+1}.
__global__ __launch_bounds__(256) void prop_ln(const float* __restrict__ h0,
                                               const int* __restrict__ offs,
                                               const int2* __restrict__ edge,
                                               const float* __restrict__ dinv,
                                               const float* __restrict__ b1,
                                               const float* __restrict__ gamma,
                                               const float* __restrict__ beta,
                                               float* __restrict__ h1, int n) {
    int wid = __builtin_amdgcn_readfirstlane((blockIdx.x * blockDim.x + threadIdx.x) >> 6);
    int lane = threadIdx.x & 63;
    if (wid >= n) return;
    const float2* __restrict__ h02 = (const float2*)h0;
    float di = dinv[wid];
    float2 v = h02[wid * 64 + lane];
    float a0 = v.x * di * di;      // self loop, norm = dinv^2
    float a1 = v.y * di * di;
    int s0 = offs[wid], s1 = offs[wid + 1];
    for (int k = s0; k < s1; ++k) {
        int2 ed = edge[k];         // wave-uniform -> scalar load
        float w = __int_as_float(ed.y);
        float2 u = h02[ed.x * 64 + lane];
        a0 = fmaf(u.x, w, a0);
        a1 = fmaf(u.y, w, a1);
    }
    a0 += b1[2 * lane];
    a1 += b1[2 * lane + 1];
    // LayerNorm over 128 features spread across the 64-lane wave
    float sum = a0 + a1, sq = a0 * a0 + a1 * a1;
#pragma unroll
    for (int off = 32; off > 0; off >>= 1) {
        sum += __shfl_xor(sum, off);
        sq  += __shfl_xor(sq, off);
    }
    float mu  = sum * (1.f / 128.f);
    float var = fmaxf(sq * (1.f / 128.f) - mu * mu, 0.f);
    float rstd = rsqrtf(var + 1e-6f);
    float y0 = fmaxf((a0 - mu) * rstd * gamma[2 * lane] + beta[2 * lane], 0.f);
    float y1 = fmaxf((a1 - mu) * rstd * gamma[2 * lane + 1] + beta[2 * lane + 1], 0.f);
    ((float2*)h1)[wid * 64 + lane] = make_float2(y0, y1);
}

// Layer 2 propagation + bias. One wave per node, lane = feature (64).
__global__ __launch_bounds__(256) void prop_out(const float* __restrict__ h2,
                                                const int* __restrict__ offs,
                                                const int2* __restrict__ edge,
                                                const float* __restrict__ dinv,
                                                const float* __restrict__ b2,
                                                float* __restrict__ out, int n) {
    int wid = __builtin_amdgcn_readfirstlane((blockIdx.x * blockDim.x + threadIdx.x) >> 6);
    int lane = threadIdx.x & 63;
    if (wid >= n) return;
    float di = dinv[wid];
    float a = h2[wid * 64 + lane] * di * di;
    int s0 = offs[wid], s1 = offs[wid + 1];
    for (int k = s0; k < s1; ++k) {
        int2 ed = edge[k];
        a = fmaf(h2[ed.x * 64 + lane], __int_as_float(ed.y), a);
    }
    out[wid * 64 + lane] = a + b2[lane];
}

extern "C" void kernel_launch(void* const* d_in, const int* in_sizes, int n_in,
                              void* d_out, int out_size, void* d_ws, size_t ws_size,
                              hipStream_t stream) {
    const float* x     = (const float*)d_in[0];
    const int*   ei    = (const int*)d_in[1];
    const float* W1    = (const float*)d_in[2];
    const float* b1    = (const float*)d_in[3];
    const float* gam   = (const float*)d_in[4];
    const float* bet   = (const float*)d_in[5];
    const float* W2    = (const float*)d_in[6];
    const float* b2    = (const float*)d_in[7];
    float* out = (float*)d_out;

    int n = in_sizes[0] / 128;   // 50000
    int e = in_sizes[1] / 2;     // 800000
    const int* src = ei;
    const int* dst = ei + e;

    char* p = (char*)d_ws;
    auto alloc = [&](size_t bytes) {
        void* q = (void*)p;
        p += (bytes + 255) & ~(size_t)255;
        return q;
    };
    int*   cnt    = (int*)alloc((size_t)n * 4);
    int*   offs   = (int*)alloc((size_t)(n + 1) * 4);
    int*   cursor = (int*)alloc((size_t)n * 4);
    float* dinv   = (float*)alloc((size_t)n * 4);
    int2*  edge   = (int2*)alloc((size_t)e * 8);
    float* h0     = (float*)alloc((size_t)n * 128 * 4);
    float* h1     = (float*)alloc((size_t)n * 128 * 4);
    float* h2     = h0;  // reuse: h0 dead after prop_ln

    // Scan scratch aliases h0 (h0 is first written by gemm1, after the scan).
    int* incl = (int*)h0;
    int* bsum = incl + n;
    int* bpre = bsum + 64;

    int nb = (n + 1023) / 1024;  // 49 blocks for n=50000

    hipMemsetAsync(cnt, 0, (size_t)n * 4, stream);
    count_k<<<(e + 255) / 256, 256, 0, stream>>>(dst, cnt, e);
    scan1_k<<<nb, 1024, 0, stream>>>(cnt, incl, bsum, n);
    scan2_k<<<1, 64, 0, stream>>>(bsum, bpre, nb);
    scan3_k<<<nb, 1024, 0, stream>>>(cnt, incl, bpre, offs, cursor, dinv, n);
    fill_k<<<(e + 255) / 256, 256, 0, stream>>>(src, dst, cursor, dinv, edge, e);

    gemm_rt<128><<<dim3((n + 255) / 256, 4), 256, 0, stream>>>(x, W1, h0, n);
    prop_ln<<<(n + 3) / 4, 256, 0, stream>>>(h0, offs, edge, dinv, b1, gam, bet, h1, n);
    gemm_rt<64><<<dim3((n + 255) / 256, 2), 256, 0, stream>>>(h1, W2, h2, n);
    prop_out<<<(n + 3) / 4, 256, 0, stream>>>(h2, offs, edge, dinv, b2, out, n);
}

// Round 3
// 271.227 us; speedup vs baseline: 1.5082x; 1.1576x over previous
//
#include <hip/hip_runtime.h>

// ---------------------------------------------------------------------------
// GCN 2-layer: h1 = relu(LN(Ahat @ (x W1) + b1)); out = Ahat @ (h1 W2) + b2
// Ahat = D^-1/2 (A+I) D^-1/2, CSR built on-device each call (no feature atomics)
// Round 1: single-block scan (133us, 1 CU) -> hierarchical scan.
// Round 2: gemm_rt (70us, 220MB fetch = 8.6x over-read: y-replication + L2
//          thrash from 16B/lane stride-512 loads) -> LDS-tiled gemm_lds
//          (coalesced 32KB stripe stage, no column replication).
// ---------------------------------------------------------------------------

__global__ void count_k(const int* __restrict__ dst, int* __restrict__ cnt, int e) {
    int i = blockIdx.x * blockDim.x + threadIdx.x;
    if (i < e) atomicAdd(&cnt[dst[i]], 1);
}

// Pass 1: per-block inclusive scan of cnt -> incl, block totals -> bsum.
__global__ __launch_bounds__(1024) void scan1_k(const int* __restrict__ cnt,
                                                int* __restrict__ incl,
                                                int* __restrict__ bsum, int n) {
    __shared__ int lds[1024];
    int t = threadIdx.x;
    int i = blockIdx.x * 1024 + t;
    int v = (i < n) ? cnt[i] : 0;
    lds[t] = v;
    __syncthreads();
#pragma unroll
    for (int d = 1; d < 1024; d <<= 1) {
        int u = (t >= d) ? lds[t - d] : 0;
        __syncthreads();
        lds[t] += u;
        __syncthreads();
    }
    if (i < n) incl[i] = lds[t];
    if (t == 1023) bsum[blockIdx.x] = lds[1023];
}

// Pass 2: exclusive scan of the block sums (single wave).
__global__ __launch_bounds__(64) void scan2_k(const int* __restrict__ bsum,
                                              int* __restrict__ bpre, int nb) {
    int t = threadIdx.x;
    int v = (t < nb) ? bsum[t] : 0;
#pragma unroll
    for (int d = 1; d < 64; d <<= 1) {
        int u = __shfl_up(v, d);
        if (t >= d) v += u;
    }
    if (t < nb) bpre[t] = v - bsum[t];   // exclusive
}

// Pass 3: offs/cursor (exclusive prefix), dinv, sentinel offs[n].
__global__ __launch_bounds__(1024) void scan3_k(const int* __restrict__ cnt,
                                                const int* __restrict__ incl,
                                                const int* __restrict__ bpre,
                                                int* __restrict__ offs,
                                                int* __restrict__ cursor,
                                                float* __restrict__ dinv, int n) {
    int i = blockIdx.x * 1024 + threadIdx.x;
    if (i >= n) return;
    int c = cnt[i];
    int inc = incl[i] + bpre[blockIdx.x];
    int ex = inc - c;
    offs[i] = ex;
    cursor[i] = ex;
    dinv[i] = rsqrtf((float)(c + 1));    // deg includes self loop
    if (i == n - 1) offs[n] = inc;
}

__global__ void fill_k(const int* __restrict__ src, const int* __restrict__ dst,
                       int* __restrict__ cursor, const float* __restrict__ dinv,
                       int2* __restrict__ edge, int e) {
    int i = blockIdx.x * blockDim.x + threadIdx.x;
    if (i >= e) return;
    int s = src[i], d = dst[i];
    int pos = atomicAdd(&cursor[d], 1);
    edge[pos] = make_int2(s, __float_as_int(dinv[s] * dinv[d]));
}

// LDS-tiled GEMM: X[n,128] @ W[128,M] -> H[n,M].
// Block = 64 rows x M cols, 4 waves; wave w owns cols [w*M/4, (w+1)*M/4).
// X stripe (64x128 f32 = 32KB contiguous) staged coalesced into LDS, rows
// padded to 129 floats: compute reads Xs[lane][k] hit bank (lane+k)%32 ->
// 2 lanes/bank (free). W reads are wave-uniform -> scalar s_load (K$).
template<int M>
__global__ __launch_bounds__(256) void gemm_lds(const float* __restrict__ X,
                                                const float* __restrict__ W,
                                                float* __restrict__ H, int n) {
    __shared__ float Xs[64][129];
    int r0 = blockIdx.x * 64;
    int t = threadIdx.x;
    int rows = min(64, n - r0);
    const float4* X4 = (const float4*)(X + (size_t)r0 * 128);
#pragma unroll
    for (int i = 0; i < 8; ++i) {
        int u = t + i * 256;          // float4 index within stripe
        int row = u >> 5;             // 32 float4 per row
        if (row < rows) {
            float4 v = X4[u];
            int col = (u & 31) << 2;
            Xs[row][col]     = v.x;
            Xs[row][col + 1] = v.y;
            Xs[row][col + 2] = v.z;
            Xs[row][col + 3] = v.w;
        }
    }
    __syncthreads();

    constexpr int CW = M / 4;         // cols per wave (32 or 16)
    int wv = __builtin_amdgcn_readfirstlane(t >> 6);
    int lane = t & 63;
    int c0 = wv * CW;
    if (lane >= rows) return;

    float acc[CW];
#pragma unroll
    for (int j = 0; j < CW; ++j) acc[j] = 0.f;

    for (int k = 0; k < 128; k += 4) {
        float x0 = Xs[lane][k];
        float x1 = Xs[lane][k + 1];
        float x2 = Xs[lane][k + 2];
        float x3 = Xs[lane][k + 3];
        const float* Wk = &W[(size_t)k * M + c0];
#pragma unroll
        for (int j = 0; j < CW; ++j) {
            float a = acc[j];
            a = fmaf(x0, Wk[j], a);
            a = fmaf(x1, Wk[M + j], a);
            a = fmaf(x2, Wk[2 * M + j], a);
            a = fmaf(x3, Wk[3 * M + j], a);
            acc[j] = a;
        }
    }

    float* Hp = &H[(size_t)(r0 + lane) * M + c0];
#pragma unroll
    for (int j = 0; j < CW; j += 4)
        *(float4*)&Hp[j] = make_float4(acc[j], acc[j + 1], acc[j + 2], acc[j + 3]);
}

// Layer 1 propagation + bias + LayerNorm + ReLU. One wave per node,
// lane holds features {2*lane, 2*lane+1}.
__global__ __launch_bounds__(256) void prop_ln(const float* __restrict__ h0,
                                               const int* __restrict__ offs,
                                               const int2* __restrict__ edge,
                                               const float* __restrict__ dinv,
                                               const float* __restrict__ b1,
                                               const float* __restrict__ gamma,
                                               const float* __restrict__ beta,
                                               float* __restrict__ h1, int n) {
    int wid = __builtin_amdgcn_readfirstlane((blockIdx.x * blockDim.x + threadIdx.x) >> 6);
    int lane = threadIdx.x & 63;
    if (wid >= n) return;
    const float2* __restrict__ h02 = (const float2*)h0;
    float di = dinv[wid];
    float2 v = h02[wid * 64 + lane];
    float a0 = v.x * di * di;      // self loop, norm = dinv^2
    float a1 = v.y * di * di;
    int s0 = offs[wid], s1 = offs[wid + 1];
    for (int k = s0; k < s1; ++k) {
        int2 ed = edge[k];         // wave-uniform -> scalar load
        float w = __int_as_float(ed.y);
        float2 u = h02[ed.x * 64 + lane];
        a0 = fmaf(u.x, w, a0);
        a1 = fmaf(u.y, w, a1);
    }
    a0 += b1[2 * lane];
    a1 += b1[2 * lane + 1];
    // LayerNorm over 128 features spread across the 64-lane wave
    float sum = a0 + a1, sq = a0 * a0 + a1 * a1;
#pragma unroll
    for (int off = 32; off > 0; off >>= 1) {
        sum += __shfl_xor(sum, off);
        sq  += __shfl_xor(sq, off);
    }
    float mu  = sum * (1.f / 128.f);
    float var = fmaxf(sq * (1.f / 128.f) - mu * mu, 0.f);
    float rstd = rsqrtf(var + 1e-6f);
    float y0 = fmaxf((a0 - mu) * rstd * gamma[2 * lane] + beta[2 * lane], 0.f);
    float y1 = fmaxf((a1 - mu) * rstd * gamma[2 * lane + 1] + beta[2 * lane + 1], 0.f);
    ((float2*)h1)[wid * 64 + lane] = make_float2(y0, y1);
}

// Layer 2 propagation + bias. One wave per node, lane = feature (64).
__global__ __launch_bounds__(256) void prop_out(const float* __restrict__ h2,
                                                const int* __restrict__ offs,
                                                const int2* __restrict__ edge,
                                                const float* __restrict__ dinv,
                                                const float* __restrict__ b2,
                                                float* __restrict__ out, int n) {
    int wid = __builtin_amdgcn_readfirstlane((blockIdx.x * blockDim.x + threadIdx.x) >> 6);
    int lane = threadIdx.x & 63;
    if (wid >= n) return;
    float di = dinv[wid];
    float a = h2[wid * 64 + lane] * di * di;
    int s0 = offs[wid], s1 = offs[wid + 1];
    for (int k = s0; k < s1; ++k) {
        int2 ed = edge[k];
        a = fmaf(h2[ed.x * 64 + lane], __int_as_float(ed.y), a);
    }
    out[wid * 64 + lane] = a + b2[lane];
}

extern "C" void kernel_launch(void* const* d_in, const int* in_sizes, int n_in,
                              void* d_out, int out_size, void* d_ws, size_t ws_size,
                              hipStream_t stream) {
    const float* x     = (const float*)d_in[0];
    const int*   ei    = (const int*)d_in[1];
    const float* W1    = (const float*)d_in[2];
    const float* b1    = (const float*)d_in[3];
    const float* gam   = (const float*)d_in[4];
    const float* bet   = (const float*)d_in[5];
    const float* W2    = (const float*)d_in[6];
    const float* b2    = (const float*)d_in[7];
    float* out = (float*)d_out;

    int n = in_sizes[0] / 128;   // 50000
    int e = in_sizes[1] / 2;     // 800000
    const int* src = ei;
    const int* dst = ei + e;

    char* p = (char*)d_ws;
    auto alloc = [&](size_t bytes) {
        void* q = (void*)p;
        p += (bytes + 255) & ~(size_t)255;
        return q;
    };
    int*   cnt    = (int*)alloc((size_t)n * 4);
    int*   offs   = (int*)alloc((size_t)(n + 1) * 4);
    int*   cursor = (int*)alloc((size_t)n * 4);
    float* dinv   = (float*)alloc((size_t)n * 4);
    int2*  edge   = (int2*)alloc((size_t)e * 8);
    float* h0     = (float*)alloc((size_t)n * 128 * 4);
    float* h1     = (float*)alloc((size_t)n * 128 * 4);
    float* h2     = h0;  // reuse: h0 dead after prop_ln

    // Scan scratch aliases h0 (h0 is first written by gemm1, after the scan).
    int* incl = (int*)h0;
    int* bsum = incl + n;
    int* bpre = bsum + 64;

    int nb = (n + 1023) / 1024;  // 49 blocks for n=50000

    hipMemsetAsync(cnt, 0, (size_t)n * 4, stream);
    count_k<<<(e + 255) / 256, 256, 0, stream>>>(dst, cnt, e);
    scan1_k<<<nb, 1024, 0, stream>>>(cnt, incl, bsum, n);
    scan2_k<<<1, 64, 0, stream>>>(bsum, bpre, nb);
    scan3_k<<<nb, 1024, 0, stream>>>(cnt, incl, bpre, offs, cursor, dinv, n);
    fill_k<<<(e + 255) / 256, 256, 0, stream>>>(src, dst, cursor, dinv, edge, e);

    int gb = (n + 63) / 64;      // 782 blocks
    gemm_lds<128><<<gb, 256, 0, stream>>>(x, W1, h0, n);
    prop_ln<<<(n + 3) / 4, 256, 0, stream>>>(h0, offs, edge, dinv, b1, gam, bet, h1, n);
    gemm_lds<64><<<gb, 256, 0, stream>>>(h1, W2, h2, n);
    prop_out<<<(n + 3) / 4, 256, 0, stream>>>(h2, offs, edge, dinv, b2, out, n);
}

// Round 4
// 230.958 us; speedup vs baseline: 1.7711x; 1.1744x over previous
//
#include <hip/hip_runtime.h>

// ---------------------------------------------------------------------------
// GCN 2-layer: h1 = relu(LN(Ahat @ (x W1) + b1)); out = Ahat @ (h1 W2) + b2
// Ahat = D^-1/2 (A+I) D^-1/2, CSR built on-device each call (no feature atomics)
// Round 1: single-block scan (133us, 1 CU) -> hierarchical scan.
// Round 2: gemm_rt (70us, 220MB fetch) -> LDS-tiled gemm_lds.
// Round 3: prop kernels were latency-serial (1 outstanding gather/wave) ->
//          4-deep pipelined gathers; h0 table f32->packed bf16 (pre-LN, so
//          LN renormalizes the rounding noise; halves gather bytes).
// ---------------------------------------------------------------------------

__device__ __forceinline__ unsigned short f2bf(float f) {
    unsigned u = __float_as_uint(f);
    u += 0x7FFF + ((u >> 16) & 1);     // round-to-nearest-even
    return (unsigned short)(u >> 16);
}
__device__ __forceinline__ float bfLo(unsigned g) { return __uint_as_float(g << 16); }
__device__ __forceinline__ float bfHi(unsigned g) { return __uint_as_float(g & 0xFFFF0000u); }

__global__ void count_k(const int* __restrict__ dst, int* __restrict__ cnt, int e) {
    int i = blockIdx.x * blockDim.x + threadIdx.x;
    if (i < e) atomicAdd(&cnt[dst[i]], 1);
}

// Pass 1: per-block inclusive scan of cnt -> incl, block totals -> bsum.
__global__ __launch_bounds__(1024) void scan1_k(const int* __restrict__ cnt,
                                                int* __restrict__ incl,
                                                int* __restrict__ bsum, int n) {
    __shared__ int lds[1024];
    int t = threadIdx.x;
    int i = blockIdx.x * 1024 + t;
    int v = (i < n) ? cnt[i] : 0;
    lds[t] = v;
    __syncthreads();
#pragma unroll
    for (int d = 1; d < 1024; d <<= 1) {
        int u = (t >= d) ? lds[t - d] : 0;
        __syncthreads();
        lds[t] += u;
        __syncthreads();
    }
    if (i < n) incl[i] = lds[t];
    if (t == 1023) bsum[blockIdx.x] = lds[1023];
}

// Pass 2: exclusive scan of the block sums (single wave).
__global__ __launch_bounds__(64) void scan2_k(const int* __restrict__ bsum,
                                              int* __restrict__ bpre, int nb) {
    int t = threadIdx.x;
    int v = (t < nb) ? bsum[t] : 0;
#pragma unroll
    for (int d = 1; d < 64; d <<= 1) {
        int u = __shfl_up(v, d);
        if (t >= d) v += u;
    }
    if (t < nb) bpre[t] = v - bsum[t];   // exclusive
}

// Pass 3: offs/cursor (exclusive prefix), dinv, sentinel offs[n].
__global__ __launch_bounds__(1024) void scan3_k(const int* __restrict__ cnt,
                                                const int* __restrict__ incl,
                                                const int* __restrict__ bpre,
                                                int* __restrict__ offs,
                                                int* __restrict__ cursor,
                                                float* __restrict__ dinv, int n) {
    int i = blockIdx.x * 1024 + threadIdx.x;
    if (i >= n) return;
    int c = cnt[i];
    int inc = incl[i] + bpre[blockIdx.x];
    int ex = inc - c;
    offs[i] = ex;
    cursor[i] = ex;
    dinv[i] = rsqrtf((float)(c + 1));    // deg includes self loop
    if (i == n - 1) offs[n] = inc;
}

__global__ void fill_k(const int* __restrict__ src, const int* __restrict__ dst,
                       int* __restrict__ cursor, const float* __restrict__ dinv,
                       int2* __restrict__ edge, int e) {
    int i = blockIdx.x * blockDim.x + threadIdx.x;
    if (i >= e) return;
    int s = src[i], d = dst[i];
    int pos = atomicAdd(&cursor[d], 1);
    edge[pos] = make_int2(s, __float_as_int(dinv[s] * dinv[d]));
}

// LDS-tiled GEMM: X[n,128] @ W[128,M] -> H[n,M]. Block = 64 rows, 4 waves;
// wave w owns cols [w*M/4,(w+1)*M/4). W reads wave-uniform -> s_load.
// BF16 epilogue packs col pairs {2j,2j+1} into one uint (lo,hi).
template<int M, bool BF16>
__global__ __launch_bounds__(256) void gemm_lds(const float* __restrict__ X,
                                                const float* __restrict__ W,
                                                void* __restrict__ Hv, int n) {
    __shared__ float Xs[64][129];
    int r0 = blockIdx.x * 64;
    int t = threadIdx.x;
    int rows = min(64, n - r0);
    const float4* X4 = (const float4*)(X + (size_t)r0 * 128);
#pragma unroll
    for (int i = 0; i < 8; ++i) {
        int u = t + i * 256;          // float4 index within stripe
        int row = u >> 5;             // 32 float4 per row
        if (row < rows) {
            float4 v = X4[u];
            int col = (u & 31) << 2;
            Xs[row][col]     = v.x;
            Xs[row][col + 1] = v.y;
            Xs[row][col + 2] = v.z;
            Xs[row][col + 3] = v.w;
        }
    }
    __syncthreads();

    constexpr int CW = M / 4;         // cols per wave (32 or 16)
    int wv = __builtin_amdgcn_readfirstlane(t >> 6);
    int lane = t & 63;
    int c0 = wv * CW;
    if (lane >= rows) return;

    float acc[CW];
#pragma unroll
    for (int j = 0; j < CW; ++j) acc[j] = 0.f;

    for (int k = 0; k < 128; k += 4) {
        float x0 = Xs[lane][k];
        float x1 = Xs[lane][k + 1];
        float x2 = Xs[lane][k + 2];
        float x3 = Xs[lane][k + 3];
        const float* Wk = &W[(size_t)k * M + c0];
#pragma unroll
        for (int j = 0; j < CW; ++j) {
            float a = acc[j];
            a = fmaf(x0, Wk[j], a);
            a = fmaf(x1, Wk[M + j], a);
            a = fmaf(x2, Wk[2 * M + j], a);
            a = fmaf(x3, Wk[3 * M + j], a);
            acc[j] = a;
        }
    }

    if constexpr (BF16) {
        unsigned pk[CW / 2];
#pragma unroll
        for (int j = 0; j < CW / 2; ++j)
            pk[j] = (unsigned)f2bf(acc[2 * j]) | ((unsigned)f2bf(acc[2 * j + 1]) << 16);
        unsigned* Hb = (unsigned*)Hv + (size_t)(r0 + lane) * (M / 2) + c0 / 2;
#pragma unroll
        for (int j = 0; j < CW / 2; j += 4)
            *(uint4*)&Hb[j] = make_uint4(pk[j], pk[j + 1], pk[j + 2], pk[j + 3]);
    } else {
        float* Hp = (float*)Hv + (size_t)(r0 + lane) * M + c0;
#pragma unroll
        for (int j = 0; j < CW; j += 4)
            *(float4*)&Hp[j] = make_float4(acc[j], acc[j + 1], acc[j + 2], acc[j + 3]);
    }
}

// Layer 1 propagation + bias + LayerNorm + ReLU. One wave per node, lane
// holds features {2*lane, 2*lane+1} (one packed-bf16 uint). Edge loop is a
// 4-deep software pipeline: 4 row-gathers in flight, next 4 edge descriptors
// prefetched (wave-uniform -> scalar loads). Tail padded with zero-weight.
__global__ __launch_bounds__(256) void prop_ln(const unsigned* __restrict__ h0b,
                                               const int* __restrict__ offs,
                                               const int2* __restrict__ edge,
                                               const float* __restrict__ dinv,
                                               const float* __restrict__ b1,
                                               const float* __restrict__ gamma,
                                               const float* __restrict__ beta,
                                               float* __restrict__ h1, int n) {
    int wid = __builtin_amdgcn_readfirstlane((blockIdx.x * blockDim.x + threadIdx.x) >> 6);
    int lane = threadIdx.x & 63;
    if (wid >= n) return;
    float di = dinv[wid];
    unsigned self = h0b[(size_t)wid * 64 + lane];
    float a0 = bfLo(self) * di * di;   // self loop, norm = dinv^2
    float a1 = bfHi(self) * di * di;

    int s0 = offs[wid], s1 = offs[wid + 1];
    int k = s0;
    int2 e4[4];
#pragma unroll
    for (int j = 0; j < 4; ++j) e4[j] = (k + j < s1) ? edge[k + j] : make_int2(0, 0);
    while (k < s1) {
        unsigned g[4];
        float w[4];
#pragma unroll
        for (int j = 0; j < 4; ++j) {
            w[j] = __int_as_float(e4[j].y);
            g[j] = h0b[(size_t)e4[j].x * 64 + lane];
        }
        k += 4;
#pragma unroll
        for (int j = 0; j < 4; ++j) e4[j] = (k + j < s1) ? edge[k + j] : make_int2(0, 0);
#pragma unroll
        for (int j = 0; j < 4; ++j) {
            a0 = fmaf(bfLo(g[j]), w[j], a0);
            a1 = fmaf(bfHi(g[j]), w[j], a1);
        }
    }

    a0 += b1[2 * lane];
    a1 += b1[2 * lane + 1];
    // LayerNorm over 128 features spread across the 64-lane wave
    float sum = a0 + a1, sq = a0 * a0 + a1 * a1;
#pragma unroll
    for (int off = 32; off > 0; off >>= 1) {
        sum += __shfl_xor(sum, off);
        sq  += __shfl_xor(sq, off);
    }
    float mu  = sum * (1.f / 128.f);
    float var = fmaxf(sq * (1.f / 128.f) - mu * mu, 0.f);
    float rstd = rsqrtf(var + 1e-6f);
    float y0 = fmaxf((a0 - mu) * rstd * gamma[2 * lane] + beta[2 * lane], 0.f);
    float y1 = fmaxf((a1 - mu) * rstd * gamma[2 * lane + 1] + beta[2 * lane + 1], 0.f);
    ((float2*)h1)[(size_t)wid * 64 + lane] = make_float2(y0, y1);
}

// Layer 2 propagation + bias (f32 gathers, same 4-deep pipeline).
__global__ __launch_bounds__(256) void prop_out(const float* __restrict__ h2,
                                                const int* __restrict__ offs,
                                                const int2* __restrict__ edge,
                                                const float* __restrict__ dinv,
                                                const float* __restrict__ b2,
                                                float* __restrict__ out, int n) {
    int wid = __builtin_amdgcn_readfirstlane((blockIdx.x * blockDim.x + threadIdx.x) >> 6);
    int lane = threadIdx.x & 63;
    if (wid >= n) return;
    float di = dinv[wid];
    float a = h2[(size_t)wid * 64 + lane] * di * di;

    int s0 = offs[wid], s1 = offs[wid + 1];
    int k = s0;
    int2 e4[4];
#pragma unroll
    for (int j = 0; j < 4; ++j) e4[j] = (k + j < s1) ? edge[k + j] : make_int2(0, 0);
    while (k < s1) {
        float g[4], w[4];
#pragma unroll
        for (int j = 0; j < 4; ++j) {
            w[j] = __int_as_float(e4[j].y);
            g[j] = h2[(size_t)e4[j].x * 64 + lane];
        }
        k += 4;
#pragma unroll
        for (int j = 0; j < 4; ++j) e4[j] = (k + j < s1) ? edge[k + j] : make_int2(0, 0);
#pragma unroll
        for (int j = 0; j < 4; ++j) a = fmaf(g[j], w[j], a);
    }
    out[(size_t)wid * 64 + lane] = a + b2[lane];
}

extern "C" void kernel_launch(void* const* d_in, const int* in_sizes, int n_in,
                              void* d_out, int out_size, void* d_ws, size_t ws_size,
                              hipStream_t stream) {
    const float* x     = (const float*)d_in[0];
    const int*   ei    = (const int*)d_in[1];
    const float* W1    = (const float*)d_in[2];
    const float* b1    = (const float*)d_in[3];
    const float* gam   = (const float*)d_in[4];
    const float* bet   = (const float*)d_in[5];
    const float* W2    = (const float*)d_in[6];
    const float* b2    = (const float*)d_in[7];
    float* out = (float*)d_out;

    int n = in_sizes[0] / 128;   // 50000
    int e = in_sizes[1] / 2;     // 800000
    const int* src = ei;
    const int* dst = ei + e;

    char* p = (char*)d_ws;
    auto alloc = [&](size_t bytes) {
        void* q = (void*)p;
        p += (bytes + 255) & ~(size_t)255;
        return q;
    };
    int*      cnt    = (int*)alloc((size_t)n * 4);
    int*      offs   = (int*)alloc((size_t)(n + 1) * 4);
    int*      cursor = (int*)alloc((size_t)n * 4);
    float*    dinv   = (float*)alloc((size_t)n * 4);
    int2*     edge   = (int2*)alloc((size_t)e * 8);
    unsigned* h0b    = (unsigned*)alloc((size_t)n * 64 * 4);  // packed bf16 [n][64]
    float*    h1     = (float*)alloc((size_t)n * 128 * 4);
    float*    h2     = (float*)h0b;  // f32 [n][64], aliases h0b (dead after prop_ln)

    // Scan scratch aliases h0b (first written by gemm1, after the scan).
    int* incl = (int*)h0b;
    int* bsum = incl + n;
    int* bpre = bsum + 64;

    int nb = (n + 1023) / 1024;  // 49 blocks for n=50000

    hipMemsetAsync(cnt, 0, (size_t)n * 4, stream);
    count_k<<<(e + 255) / 256, 256, 0, stream>>>(dst, cnt, e);
    scan1_k<<<nb, 1024, 0, stream>>>(cnt, incl, bsum, n);
    scan2_k<<<1, 64, 0, stream>>>(bsum, bpre, nb);
    scan3_k<<<nb, 1024, 0, stream>>>(cnt, incl, bpre, offs, cursor, dinv, n);
    fill_k<<<(e + 255) / 256, 256, 0, stream>>>(src, dst, cursor, dinv, edge, e);

    int gb = (n + 63) / 64;      // 782 blocks
    gemm_lds<128, true><<<gb, 256, 0, stream>>>(x, W1, h0b, n);
    prop_ln<<<(n + 3) / 4, 256, 0, stream>>>(h0b, offs, edge, dinv, b1, gam, bet, h1, n);
    gemm_lds<64, false><<<gb, 256, 0, stream>>>(h1, W2, h2, n);
    prop_out<<<(n + 3) / 4, 256, 0, stream>>>(h2, offs, edge, dinv, b2, out, n);
}

// Round 5
// 229.313 us; speedup vs baseline: 1.7838x; 1.0072x over previous
//
#include <hip/hip_runtime.h>

// ---------------------------------------------------------------------------
// GCN 2-layer: h1 = relu(LN(Ahat @ (x W1) + b1)); out = Ahat @ (h1 W2) + b2
// Ahat = D^-1/2 (A+I) D^-1/2, CSR built on-device each call (no feature atomics)
// Round 1: single-block scan (133us, 1 CU) -> hierarchical scan.
// Round 2: gemm_rt (70us, 220MB fetch) -> LDS-tiled gemm_lds.
// Round 3: prop kernels latency-serial -> 4-deep pipelined gathers; h0 -> bf16.
// Round 4: fill_k wrote 52.8MB for a 6.4MB array (partial-line thrash, target
//          > per-XCD L2) -> 4B payload (src only; weight recomputed in prop
//          from L2-resident dinv), rank folded into count_k's atomic return
//          (fill has zero atomics), 8-deep gather pipeline, h2 table -> bf16.
// ---------------------------------------------------------------------------

__device__ __forceinline__ unsigned short f2bf(float f) {
    unsigned u = __float_as_uint(f);
    u += 0x7FFF + ((u >> 16) & 1);     // round-to-nearest-even
    return (unsigned short)(u >> 16);
}
__device__ __forceinline__ float bfLo(unsigned g) { return __uint_as_float(g << 16); }
__device__ __forceinline__ float bfHi(unsigned g) { return __uint_as_float(g & 0xFFFF0000u); }
__device__ __forceinline__ float bfU(unsigned short u) { return __uint_as_float((unsigned)u << 16); }

// count + rank in one pass: rank = arrival order within dst bucket.
__global__ void count_k(const int* __restrict__ dst, int* __restrict__ cnt,
                        int* __restrict__ rank, int e) {
    int i = blockIdx.x * blockDim.x + threadIdx.x;
    if (i < e) rank[i] = atomicAdd(&cnt[dst[i]], 1);
}

// Pass 1: per-block inclusive scan of cnt -> incl, block totals -> bsum.
__global__ __launch_bounds__(1024) void scan1_k(const int* __restrict__ cnt,
                                                int* __restrict__ incl,
                                                int* __restrict__ bsum, int n) {
    __shared__ int lds[1024];
    int t = threadIdx.x;
    int i = blockIdx.x * 1024 + t;
    int v = (i < n) ? cnt[i] : 0;
    lds[t] = v;
    __syncthreads();
#pragma unroll
    for (int d = 1; d < 1024; d <<= 1) {
        int u = (t >= d) ? lds[t - d] : 0;
        __syncthreads();
        lds[t] += u;
        __syncthreads();
    }
    if (i < n) incl[i] = lds[t];
    if (t == 1023) bsum[blockIdx.x] = lds[1023];
}

// Pass 2: exclusive scan of the block sums (single wave).
__global__ __launch_bounds__(64) void scan2_k(const int* __restrict__ bsum,
                                              int* __restrict__ bpre, int nb) {
    int t = threadIdx.x;
    int v = (t < nb) ? bsum[t] : 0;
#pragma unroll
    for (int d = 1; d < 64; d <<= 1) {
        int u = __shfl_up(v, d);
        if (t >= d) v += u;
    }
    if (t < nb) bpre[t] = v - bsum[t];   // exclusive
}

// Pass 3: offs (exclusive prefix), dinv, sentinel offs[n].
__global__ __launch_bounds__(1024) void scan3_k(const int* __restrict__ cnt,
                                                const int* __restrict__ incl,
                                                const int* __restrict__ bpre,
                                                int* __restrict__ offs,
                                                float* __restrict__ dinv, int n) {
    int i = blockIdx.x * 1024 + threadIdx.x;
    if (i >= n) return;
    int c = cnt[i];
    int inc = incl[i] + bpre[blockIdx.x];
    offs[i] = inc - c;
    dinv[i] = rsqrtf((float)(c + 1));    // deg includes self loop
    if (i == n - 1) offs[n] = inc;
}

// Scatter src ids into CSR slots. 4B payload, no atomics; 3.2MB target fits
// per-XCD L2 so partial lines coalesce before writeback.
__global__ void fill_k(const int* __restrict__ src, const int* __restrict__ dst,
                       const int* __restrict__ rank, const int* __restrict__ offs,
                       int* __restrict__ esrc, int e) {
    int i = blockIdx.x * blockDim.x + threadIdx.x;
    if (i >= e) return;
    esrc[offs[dst[i]] + rank[i]] = src[i];
}

// LDS-tiled GEMM: X[n,128] @ W[128,M] -> H[n,M]. Block = 64 rows, 4 waves;
// wave w owns cols [w*M/4,(w+1)*M/4). W reads wave-uniform -> s_load.
// BF16 epilogue packs col pairs {2j,2j+1} into one uint (lo,hi).
template<int M, bool BF16>
__global__ __launch_bounds__(256) void gemm_lds(const float* __restrict__ X,
                                                const float* __restrict__ W,
                                                void* __restrict__ Hv, int n) {
    __shared__ float Xs[64][129];
    int r0 = blockIdx.x * 64;
    int t = threadIdx.x;
    int rows = min(64, n - r0);
    const float4* X4 = (const float4*)(X + (size_t)r0 * 128);
#pragma unroll
    for (int i = 0; i < 8; ++i) {
        int u = t + i * 256;          // float4 index within stripe
        int row = u >> 5;             // 32 float4 per row
        if (row < rows) {
            float4 v = X4[u];
            int col = (u & 31) << 2;
            Xs[row][col]     = v.x;
            Xs[row][col + 1] = v.y;
            Xs[row][col + 2] = v.z;
            Xs[row][col + 3] = v.w;
        }
    }
    __syncthreads();

    constexpr int CW = M / 4;         // cols per wave (32 or 16)
    int wv = __builtin_amdgcn_readfirstlane(t >> 6);
    int lane = t & 63;
    int c0 = wv * CW;
    if (lane >= rows) return;

    float acc[CW];
#pragma unroll
    for (int j = 0; j < CW; ++j) acc[j] = 0.f;

    for (int k = 0; k < 128; k += 4) {
        float x0 = Xs[lane][k];
        float x1 = Xs[lane][k + 1];
        float x2 = Xs[lane][k + 2];
        float x3 = Xs[lane][k + 3];
        const float* Wk = &W[(size_t)k * M + c0];
#pragma unroll
        for (int j = 0; j < CW; ++j) {
            float a = acc[j];
            a = fmaf(x0, Wk[j], a);
            a = fmaf(x1, Wk[M + j], a);
            a = fmaf(x2, Wk[2 * M + j], a);
            a = fmaf(x3, Wk[3 * M + j], a);
            acc[j] = a;
        }
    }

    if constexpr (BF16) {
        unsigned pk[CW / 2];
#pragma unroll
        for (int j = 0; j < CW / 2; ++j)
            pk[j] = (unsigned)f2bf(acc[2 * j]) | ((unsigned)f2bf(acc[2 * j + 1]) << 16);
        unsigned* Hb = (unsigned*)Hv + (size_t)(r0 + lane) * (M / 2) + c0 / 2;
#pragma unroll
        for (int j = 0; j < CW / 2; j += 4)
            *(uint4*)&Hb[j] = make_uint4(pk[j], pk[j + 1], pk[j + 2], pk[j + 3]);
    } else {
        float* Hp = (float*)Hv + (size_t)(r0 + lane) * M + c0;
#pragma unroll
        for (int j = 0; j < CW; j += 4)
            *(float4*)&Hp[j] = make_float4(acc[j], acc[j + 1], acc[j + 2], acc[j + 3]);
    }
}

// Layer 1 propagation + bias + LayerNorm + ReLU. One wave per node, lane
// holds features {2*lane, 2*lane+1} (one packed-bf16 uint). 8-deep gather
// pipeline; edge weight recomputed from dinv (scalar, L2-resident).
__global__ __launch_bounds__(256) void prop_ln(const unsigned* __restrict__ h0b,
                                               const int* __restrict__ offs,
                                               const int* __restrict__ esrc,
                                               const float* __restrict__ dinv,
                                               const float* __restrict__ b1,
                                               const float* __restrict__ gamma,
                                               const float* __restrict__ beta,
                                               float* __restrict__ h1, int n) {
    int wid = __builtin_amdgcn_readfirstlane((blockIdx.x * blockDim.x + threadIdx.x) >> 6);
    int lane = threadIdx.x & 63;
    if (wid >= n) return;
    float di = dinv[wid];
    unsigned self = h0b[(size_t)wid * 64 + lane];
    float a0 = bfLo(self) * di * di;   // self loop, norm = dinv^2
    float a1 = bfHi(self) * di * di;

    int s0 = offs[wid], s1 = offs[wid + 1];
    int k = s0;
    int sj[8]; float wj[8];
#pragma unroll
    for (int j = 0; j < 8; ++j) {
        bool v = (k + j < s1);
        int s = v ? esrc[v ? k + j : 0] : wid;
        sj[j] = s;
        wj[j] = v ? dinv[s] * di : 0.f;
    }
    while (k < s1) {
        unsigned g[8];
#pragma unroll
        for (int j = 0; j < 8; ++j) g[j] = h0b[(size_t)sj[j] * 64 + lane];
        k += 8;
        int s2[8]; float w2[8];
#pragma unroll
        for (int j = 0; j < 8; ++j) {
            bool v = (k + j < s1);
            int s = v ? esrc[v ? k + j : 0] : wid;
            s2[j] = s;
            w2[j] = v ? dinv[s] * di : 0.f;
        }
#pragma unroll
        for (int j = 0; j < 8; ++j) {
            a0 = fmaf(bfLo(g[j]), wj[j], a0);
            a1 = fmaf(bfHi(g[j]), wj[j], a1);
        }
#pragma unroll
        for (int j = 0; j < 8; ++j) { sj[j] = s2[j]; wj[j] = w2[j]; }
    }

    a0 += b1[2 * lane];
    a1 += b1[2 * lane + 1];
    // LayerNorm over 128 features spread across the 64-lane wave
    float sum = a0 + a1, sq = a0 * a0 + a1 * a1;
#pragma unroll
    for (int off = 32; off > 0; off >>= 1) {
        sum += __shfl_xor(sum, off);
        sq  += __shfl_xor(sq, off);
    }
    float mu  = sum * (1.f / 128.f);
    float var = fmaxf(sq * (1.f / 128.f) - mu * mu, 0.f);
    float rstd = rsqrtf(var + 1e-6f);
    float y0 = fmaxf((a0 - mu) * rstd * gamma[2 * lane] + beta[2 * lane], 0.f);
    float y1 = fmaxf((a1 - mu) * rstd * gamma[2 * lane + 1] + beta[2 * lane + 1], 0.f);
    ((float2*)h1)[(size_t)wid * 64 + lane] = make_float2(y0, y1);
}

// Layer 2 propagation + bias. One wave per node, lane = feature (64),
// bf16 gather table, 8-deep pipeline, weight recomputed from dinv.
__global__ __launch_bounds__(256) void prop_out(const unsigned short* __restrict__ h2s,
                                                const int* __restrict__ offs,
                                                const int* __restrict__ esrc,
                                                const float* __restrict__ dinv,
                                                const float* __restrict__ b2,
                                                float* __restrict__ out, int n) {
    int wid = __builtin_amdgcn_readfirstlane((blockIdx.x * blockDim.x + threadIdx.x) >> 6);
    int lane = threadIdx.x & 63;
    if (wid >= n) return;
    float di = dinv[wid];
    float a = bfU(h2s[(size_t)wid * 64 + lane]) * di * di;

    int s0 = offs[wid], s1 = offs[wid + 1];
    int k = s0;
    int sj[8]; float wj[8];
#pragma unroll
    for (int j = 0; j < 8; ++j) {
        bool v = (k + j < s1);
        int s = v ? esrc[v ? k + j : 0] : wid;
        sj[j] = s;
        wj[j] = v ? dinv[s] * di : 0.f;
    }
    while (k < s1) {
        unsigned short g[8];
#pragma unroll
        for (int j = 0; j < 8; ++j) g[j] = h2s[(size_t)sj[j] * 64 + lane];
        k += 8;
        int s2[8]; float w2[8];
#pragma unroll
        for (int j = 0; j < 8; ++j) {
            bool v = (k + j < s1);
            int s = v ? esrc[v ? k + j : 0] : wid;
            s2[j] = s;
            w2[j] = v ? dinv[s] * di : 0.f;
        }
#pragma unroll
        for (int j = 0; j < 8; ++j) a = fmaf(bfU(g[j]), wj[j], a);
#pragma unroll
        for (int j = 0; j < 8; ++j) { sj[j] = s2[j]; wj[j] = w2[j]; }
    }
    out[(size_t)wid * 64 + lane] = a + b2[lane];
}

extern "C" void kernel_launch(void* const* d_in, const int* in_sizes, int n_in,
                              void* d_out, int out_size, void* d_ws, size_t ws_size,
                              hipStream_t stream) {
    const float* x     = (const float*)d_in[0];
    const int*   ei    = (const int*)d_in[1];
    const float* W1    = (const float*)d_in[2];
    const float* b1    = (const float*)d_in[3];
    const float* gam   = (const float*)d_in[4];
    const float* bet   = (const float*)d_in[5];
    const float* W2    = (const float*)d_in[6];
    const float* b2    = (const float*)d_in[7];
    float* out = (float*)d_out;

    int n = in_sizes[0] / 128;   // 50000
    int e = in_sizes[1] / 2;     // 800000
    const int* src = ei;
    const int* dst = ei + e;

    char* p = (char*)d_ws;
    auto alloc = [&](size_t bytes) {
        void* q = (void*)p;
        p += (bytes + 255) & ~(size_t)255;
        return q;
    };
    int*      cnt  = (int*)alloc((size_t)n * 4);
    int*      offs = (int*)alloc((size_t)(n + 1) * 4);
    int*      rank = (int*)alloc((size_t)e * 4);
    float*    dinv = (float*)alloc((size_t)n * 4);
    int*      esrc = (int*)alloc((size_t)e * 4);
    unsigned* h0b  = (unsigned*)alloc((size_t)n * 64 * 4);  // packed bf16 [n][64] (12.8MB)
    float*    h1   = (float*)alloc((size_t)n * 128 * 4);

    // h2 bf16 table aliases h0b (h0b dead after prop_ln).
    unsigned short* h2s = (unsigned short*)h0b;
    // Scan scratch also aliases h0b (dead before gemm1 writes it).
    int* incl = (int*)h0b;
    int* bsum = incl + n;
    int* bpre = bsum + 64;

    int nb = (n + 1023) / 1024;  // 49 blocks for n=50000

    hipMemsetAsync(cnt, 0, (size_t)n * 4, stream);
    count_k<<<(e + 255) / 256, 256, 0, stream>>>(dst, cnt, rank, e);
    scan1_k<<<nb, 1024, 0, stream>>>(cnt, incl, bsum, n);
    scan2_k<<<1, 64, 0, stream>>>(bsum, bpre, nb);
    scan3_k<<<nb, 1024, 0, stream>>>(cnt, incl, bpre, offs, dinv, n);
    fill_k<<<(e + 255) / 256, 256, 0, stream>>>(src, dst, rank, offs, esrc, e);

    int gb = (n + 63) / 64;      // 782 blocks
    gemm_lds<128, true><<<gb, 256, 0, stream>>>(x, W1, h0b, n);
    prop_ln<<<(n + 3) / 4, 256, 0, stream>>>(h0b, offs, esrc, dinv, b1, gam, bet, h1, n);
    gemm_lds<64, true><<<gb, 256, 0, stream>>>(h1, W2, h2s, n);
    prop_out<<<(n + 3) / 4, 256, 0, stream>>>(h2s, offs, esrc, dinv, b2, out, n);
}